// Round 4
// baseline (1491.977 us; speedup 1.0000x reference)
//
#include <hip/hip_runtime.h>

#define B_    64
#define NI    2048
#define DK    16
#define NO    32
#define DOUT  32
#define EPSQ  1e-7f

typedef unsigned u32x2 __attribute__((ext_vector_type(2)));
typedef unsigned u32x4 __attribute__((ext_vector_type(4)));

constexpr int PSEG = 32;   // partial segments per b (all reducers)

// ---------- helpers ----------
__device__ __forceinline__ unsigned pack2_bf16(float a, float b) {
    unsigned ua = __float_as_uint(a);
    unsigned ub = __float_as_uint(b);
    ua = (ua + 0x7fffu + ((ua >> 16) & 1u)) >> 16;   // RNE
    ub = (ub + 0x7fffu + ((ub >> 16) & 1u)) >> 16;
    return ua | (ub << 16);
}
__device__ __forceinline__ float bf_lo(unsigned w) { return __uint_as_float(w << 16); }
__device__ __forceinline__ float bf_hi(unsigned w) { return __uint_as_float(w & 0xffff0000u); }

// ============================================================
// u_hat layout (bf16/ushort): idx = (((b*NI + i)*4 + j)*NO + o)*8 + e, d = j*8+e
// per (b,i): 4 rows of 256 ushorts (512B each) = 2KB contiguous.
// ============================================================

// ------------------------------------------------------------
// compute_uhat v3: block = (i, o-half). 512 threads.
// t -> o2 = t&15 (o = oh*16+o2), q = (t>>4)&7 (d-quad), bh = t>>7 (b-quarter).
// W tile 16 o x 2KB staged to LDS (CU_STR=516: float4-stride 129 == 1 mod 8,
// diagonal -> no read conflicts, 16B-aligned). Each W float4 reused across
// 4 b's (acc[4][4]) -> 4x less LDS read than r2. 37KB LDS -> 4 blocks/CU.
// ------------------------------------------------------------
constexpr int CU_STR = 516;

__global__ __launch_bounds__(512, 8)
void compute_uhat(const float* __restrict__ x, const float* __restrict__ W,
                  ushort* __restrict__ U)
{
    __shared__ float Ws[16 * CU_STR];    // 33024 B
    __shared__ float xs[B_ * DK];        // 4096 B
    const int bx = blockIdx.x;
    const int i  = bx >> 1;
    const int oh = bx & 1;
    const int t  = threadIdx.x;

    // stage x[0:64, i, 0:16] (4 KB)
    if (t < 256) {
        const int b = t >> 2, k4 = t & 3;
        float4 v = *(const float4*)(x + ((size_t)b * NI + i) * DK + k4 * 4);
        *(float4*)&xs[b * DK + k4 * 4] = v;
    }

    // stage W[oh*16 .. +15, i, :, :] (32 KB) coalesced
    #pragma unroll
    for (int pp = 0; pp < 4; ++pp) {
        const int p  = t + 512 * pp;     // 0..2047
        const int oo = p >> 7;           // 0..15
        const int cc = p & 127;          // float4 within o-row
        float4 v = ((const float4*)(W + ((size_t)(oh * 16 + oo) * NI + i) * (DOUT * DK)))[cc];
        *(float4*)&Ws[oo * CU_STR + cc * 4] = v;
    }

    const int o2 = t & 15;
    const int q  = (t >> 4) & 7;      // d = 4q .. 4q+3
    const int bh = t >> 7;            // 0..3 (16 b's each)

    __syncthreads();

    const int j = q >> 1, half = q & 1;
    const int o = oh * 16 + o2;
    const float* wrow = &Ws[o2 * CU_STR + q * 64];   // rows dl: wrow[16*dl + 4*k4]

    #pragma unroll
    for (int bg = 0; bg < 4; ++bg) {
        const int b0 = bh * 16 + bg * 4;
        float acc[4][4];
        #pragma unroll
        for (int bv = 0; bv < 4; ++bv)
            #pragma unroll
            for (int dl = 0; dl < 4; ++dl) acc[bv][dl] = 0.f;

        #pragma unroll
        for (int k4 = 0; k4 < 4; ++k4) {
            float4 xr[4];
            #pragma unroll
            for (int bv = 0; bv < 4; ++bv)
                xr[bv] = *(const float4*)&xs[(b0 + bv) * DK + k4 * 4];  // broadcast
            #pragma unroll
            for (int dl = 0; dl < 4; ++dl) {
                const float4 w4 = *(const float4*)&wrow[16 * dl + 4 * k4];
                #pragma unroll
                for (int bv = 0; bv < 4; ++bv) {
                    float a = acc[bv][dl];
                    a = fmaf(w4.x, xr[bv].x, a);
                    a = fmaf(w4.y, xr[bv].y, a);
                    a = fmaf(w4.z, xr[bv].z, a);
                    a = fmaf(w4.w, xr[bv].w, a);
                    acc[bv][dl] = a;
                }
            }
        }

        #pragma unroll
        for (int bv = 0; bv < 4; ++bv) {
            const int b = b0 + bv;
            u32x2 pk;
            pk.x = pack2_bf16(acc[bv][0], acc[bv][1]);
            pk.y = pack2_bf16(acc[bv][2], acc[bv][3]);
            const size_t off = ((((size_t)b * NI + i) * 4 + j) * NO + o) * 8 + half * 4;
            __builtin_nontemporal_store(pk, (u32x2*)(U + off));
        }
    }
}

// ============================================================
// sum_u: s0[b,o,d] = (1/32) * sum_i u[b,i,o,d]. Block = (b, iseg of 64 i).
// 256 threads; c = t&127 owns one uint4 column, halves cover i-parity.
// LDS half-merge, then PART: non-atomic partial row / else atomics.
// ============================================================
template<bool PART>
__global__ __launch_bounds__(256)
void sum_u(const ushort* __restrict__ U, float* __restrict__ s0)
{
    __shared__ float red[128 * 9];     // pad 9 -> conflict-free
    const int t    = threadIdx.x;
    const int b    = blockIdx.x >> 5;
    const int iseg = blockIdx.x & 31;
    const int c    = t & 127;
    const int half = t >> 7;

    float acc[8];
    #pragma unroll
    for (int k = 0; k < 8; ++k) acc[k] = 0.f;

    const u32x4* up = (const u32x4*)U
        + ((size_t)b * NI + (size_t)iseg * (NI / PSEG) + half) * 128 + c;

    #pragma unroll 8
    for (int it = 0; it < (NI / PSEG) / 2; ++it) {
        u32x4 w = __builtin_nontemporal_load(up);
        up += 256;
        acc[0] += bf_lo(w.x); acc[1] += bf_hi(w.x);
        acc[2] += bf_lo(w.y); acc[3] += bf_hi(w.y);
        acc[4] += bf_lo(w.z); acc[5] += bf_hi(w.z);
        acc[6] += bf_lo(w.w); acc[7] += bf_hi(w.w);
    }

    if (half == 1) {
        #pragma unroll
        for (int k = 0; k < 8; ++k) red[c * 9 + k] = acc[k];
    }
    __syncthreads();
    if (half == 0) {
        #pragma unroll
        for (int k = 0; k < 8; ++k) acc[k] = (acc[k] + red[c * 9 + k]) * 0.03125f;

        const int o = c & 31, j = c >> 5;
        if (PART) {
            float* sp = s0 + ((size_t)(b * PSEG + iseg)) * 1024 + o * 32 + j * 8;
            float4 lo = {acc[0], acc[1], acc[2], acc[3]};
            float4 hi = {acc[4], acc[5], acc[6], acc[7]};
            *(float4*)sp = lo;
            *(float4*)(sp + 4) = hi;
        } else {
            float* sp = s0 + (size_t)b * 1024 + o * 32 + j * 8;
            #pragma unroll
            for (int k = 0; k < 8; ++k) atomicAdd(&sp[k], acc[k]);
        }
    }
}

// ============================================================
// routing_mid (r=1,2): block = (b, iseg of 64 i). 256 threads = 4 waves.
// One full wave per i: lane = (o = l&31, dh = l>>5 owning d = dh*16..+15).
// Prologue: vs = squash(sum of sA partials) [+ squash(sB) for R=2].
// Epilogue: LDS-swizzled reduce, then partial row write (PART) or atomics.
// ============================================================
template<int R, bool PART>
__global__ __launch_bounds__(256, 5)
void routing_mid(const ushort* __restrict__ U, const float* __restrict__ sA,
                 const float* __restrict__ sB, float* __restrict__ s_out)
{
    __shared__ float sblk[NO * DOUT];     // swizzled: (o,d) at [o*32 + ((d+o)&31)]
    __shared__ float vsh[NO][DOUT + 1];
    const int t    = threadIdx.x;
    const int b    = blockIdx.x >> 5;
    const int iseg = blockIdx.x & 31;
    const int i0   = iseg * (NI / PSEG);

    // ---- vs into vsh: thread = (oo = t>>3, dg = t&7) ----
    {
        const int oo = t >> 3;
        const int dg = t & 7;
        float4 sv;
        if (PART) {
            float4 a = {0.f, 0.f, 0.f, 0.f};
            for (int is = 0; is < PSEG; ++is) {
                float4 p = *(const float4*)(sA + ((size_t)(b * PSEG + is)) * 1024 + oo * 32 + dg * 4);
                a.x += p.x; a.y += p.y; a.z += p.z; a.w += p.w;
            }
            sv = a;
        } else {
            sv = *(const float4*)(sA + (size_t)b * 1024 + oo * 32 + dg * 4);
        }
        float sq = sv.x*sv.x + sv.y*sv.y + sv.z*sv.z + sv.w*sv.w;
        #pragma unroll
        for (int msk = 4; msk >= 1; msk >>= 1) sq += __shfl_xor(sq, msk);
        float sc = sq / (1.f + sq) * rsqrtf(sq + EPSQ);
        float v0 = sv.x * sc, v1 = sv.y * sc, v2 = sv.z * sc, v3 = sv.w * sc;
        if (R == 2) {
            float4 s2v;
            if (PART) {
                float4 a = {0.f, 0.f, 0.f, 0.f};
                for (int is = 0; is < PSEG; ++is) {
                    float4 p = *(const float4*)(sB + ((size_t)(b * PSEG + is)) * 1024 + oo * 32 + dg * 4);
                    a.x += p.x; a.y += p.y; a.z += p.z; a.w += p.w;
                }
                s2v = a;
            } else {
                s2v = *(const float4*)(sB + (size_t)b * 1024 + oo * 32 + dg * 4);
            }
            float sq2 = s2v.x*s2v.x + s2v.y*s2v.y + s2v.z*s2v.z + s2v.w*s2v.w;
            #pragma unroll
            for (int msk = 4; msk >= 1; msk >>= 1) sq2 += __shfl_xor(sq2, msk);
            float sc2 = sq2 / (1.f + sq2) * rsqrtf(sq2 + EPSQ);
            v0 += s2v.x * sc2; v1 += s2v.y * sc2; v2 += s2v.z * sc2; v3 += s2v.w * sc2;
        }
        vsh[oo][dg * 4 + 0] = v0; vsh[oo][dg * 4 + 1] = v1;
        vsh[oo][dg * 4 + 2] = v2; vsh[oo][dg * 4 + 3] = v3;
    }
    for (int n = t; n < NO * DOUT; n += 256) sblk[n] = 0.f;
    __syncthreads();

    const int lane = t & 63;
    const int o    = lane & 31;
    const int dh   = lane >> 5;       // d-half: d = dh*16 + ld
    const int wv   = t >> 6;          // wave 0..3 -> 16 i each

    float vs[16];
    #pragma unroll
    for (int ld = 0; ld < 16; ++ld) vs[ld] = vsh[o][dh * 16 + ld];

    float sacc[16];
    #pragma unroll
    for (int ld = 0; ld < 16; ++ld) sacc[ld] = 0.f;

    // per (b,i): 4*NO u32x4; rows 2dh, 2dh+1 -> d = 16dh + (0..15)
    const u32x4* up = (const u32x4*)U
        + (((size_t)b * NI + i0 + wv * 16) * 4 + 2 * dh) * NO + o;

    u32x4 c0 = __builtin_nontemporal_load(up);
    u32x4 c1 = __builtin_nontemporal_load(up + NO);
    up += 4 * NO;

    for (int ii = 0; ii < 16; ++ii) {
        u32x4 n0 = {}, n1 = {};
        const bool more = (ii < 15);   // uniform
        if (more) {
            n0 = __builtin_nontemporal_load(up);
            n1 = __builtin_nontemporal_load(up + NO);
            up += 4 * NO;
        }

        float lp = 0.f;
        #pragma unroll
        for (int wi = 0; wi < 4; ++wi) {
            lp = fmaf(vs[2*wi],     bf_lo(c0[wi]), lp);
            lp = fmaf(vs[2*wi + 1], bf_hi(c0[wi]), lp);
            lp = fmaf(vs[8 + 2*wi],     bf_lo(c1[wi]), lp);
            lp = fmaf(vs[8 + 2*wi + 1], bf_hi(c1[wi]), lp);
        }
        lp += __shfl_xor(lp, 32);    // full logit on all 64 lanes

        float mx = lp;
        #pragma unroll
        for (int msk = 16; msk >= 1; msk >>= 1) mx = fmaxf(mx, __shfl_xor(mx, msk));
        const float e = __expf(lp - mx);
        float ss = e;
        #pragma unroll
        for (int msk = 16; msk >= 1; msk >>= 1) ss += __shfl_xor(ss, msk);
        const float cc = e / ss;

        #pragma unroll
        for (int wi = 0; wi < 4; ++wi) {
            sacc[2*wi]     = fmaf(cc, bf_lo(c0[wi]), sacc[2*wi]);
            sacc[2*wi + 1] = fmaf(cc, bf_hi(c0[wi]), sacc[2*wi + 1]);
            sacc[8 + 2*wi]     = fmaf(cc, bf_lo(c1[wi]), sacc[8 + 2*wi]);
            sacc[8 + 2*wi + 1] = fmaf(cc, bf_hi(c1[wi]), sacc[8 + 2*wi + 1]);
        }

        if (more) { c0 = n0; c1 = n1; }   // no uninitialized read on last iter
    }

    // block reduce (swizzled -> 2-way max, free)
    #pragma unroll
    for (int ld = 0; ld < 16; ++ld) {
        const int d = dh * 16 + ld;
        atomicAdd(&sblk[o * 32 + ((d + o) & 31)], sacc[ld]);
    }
    __syncthreads();

    if (PART) {
        float* sp = s_out + ((size_t)(b * PSEG + iseg)) * 1024;
        for (int n = t; n < NO * DOUT; n += 256) {
            const int oo = n >> 5, dd = n & 31;
            sp[n] = sblk[oo * 32 + ((dd + oo) & 31)];
        }
    } else {
        float* sp = s_out + (size_t)b * 1024;
        for (int n = t; n < NO * DOUT; n += 256) {
            const int oo = n >> 5, dd = n & 31;
            atomicAdd(&sp[n], sblk[oo * 32 + ((dd + oo) & 31)]);
        }
    }
}

// ============================================================
// final v = squash(s2) -> out.  PART: reduce 32 partial rows first.
// ============================================================
template<bool PART>
__global__ __launch_bounds__(256)
void squash_final(const float* __restrict__ s, float* __restrict__ out)
{
    const int g = blockIdx.x * 256 + threadIdx.x;   // b*1024 + o*32 + d
    float val;
    if (PART) {
        const int b = g >> 10, slot = g & 1023;
        float a = 0.f;
        for (int is = 0; is < PSEG; ++is)
            a += s[((size_t)(b * PSEG + is)) * 1024 + slot];
        val = a;
    } else {
        val = s[g];
    }
    float sq = val * val;
    #pragma unroll
    for (int msk = 16; msk >= 1; msk >>= 1) sq += __shfl_xor(sq, msk);
    const float scale = sq / (1.f + sq) * rsqrtf(sq + EPSQ);
    out[g] = val * scale;
}

// ============================================================
// FALLBACK PATH (fused recompute; used if ws too small)
// ============================================================
constexpr int BTILE  = 16;
constexpr int ITILE  = 32;
constexpr int CHUNKS = NI / ITILE;
constexpr int GB     = B_ / BTILE;
constexpr int WROW   = DOUT * DK + 4;

__global__ __launch_bounds__(512)
void routing_pass(const float* __restrict__ x, const float* __restrict__ W,
                  const float* __restrict__ Vsum, float* __restrict__ s_out)
{
    __shared__ float W_s[NO * WROW];
    const int tid   = threadIdx.x;
    const int o     = tid & 31;
    const int bl    = tid >> 5;
    const int chunk = blockIdx.x & (CHUNKS - 1);
    const int gb    = blockIdx.x / CHUNKS;
    const int b     = gb * BTILE + bl;

    float vs[DOUT];
    {
        const float4* vp = (const float4*)(Vsum + (size_t)(b * NO + o) * DOUT);
        #pragma unroll
        for (int qq = 0; qq < 8; ++qq) {
            float4 t2 = vp[qq];
            vs[4*qq+0] = t2.x; vs[4*qq+1] = t2.y; vs[4*qq+2] = t2.z; vs[4*qq+3] = t2.w;
        }
    }
    float sacc[DOUT];
    #pragma unroll
    for (int d = 0; d < DOUT; ++d) sacc[d] = 0.f;

    const int o_ld = tid >> 4;
    const int lpos = tid & 15;

    for (int ii = 0; ii < ITILE; ++ii) {
        const int i = chunk * ITILE + ii;
        __syncthreads();
        const float4* wsrc = (const float4*)W + ((size_t)o_ld * NI + i) * (DOUT * DK / 4);
        #pragma unroll
        for (int jj = 0; jj < 8; ++jj) {
            const int f4pos = lpos + 16 * jj;
            float4 v = wsrc[f4pos];
            *(float4*)&W_s[o_ld * WROW + f4pos * 4] = v;
        }
        __syncthreads();

        const float4* xg = (const float4*)(x + ((size_t)b * NI + i) * DK);
        const float4 xr0 = xg[0], xr1 = xg[1], xr2 = xg[2], xr3 = xg[3];

        float u[DOUT];
        float logit = 0.f;
        const float* wrow = &W_s[o * WROW];
        #pragma unroll
        for (int d = 0; d < DOUT; ++d) {
            const float4 w0 = *(const float4*)(wrow + d * DK + 0);
            const float4 w1 = *(const float4*)(wrow + d * DK + 4);
            const float4 w2 = *(const float4*)(wrow + d * DK + 8);
            const float4 w3 = *(const float4*)(wrow + d * DK + 12);
            float acc;
            acc  = w0.x * xr0.x + w0.y * xr0.y + w0.z * xr0.z + w0.w * xr0.w;
            acc += w1.x * xr1.x + w1.y * xr1.y + w1.z * xr1.z + w1.w * xr1.w;
            acc += w2.x * xr2.x + w2.y * xr2.y + w2.z * xr2.z + w2.w * xr2.w;
            acc += w3.x * xr3.x + w3.y * xr3.y + w3.z * xr3.z + w3.w * xr3.w;
            u[d]  = acc;
            logit = fmaf(vs[d], acc, logit);
        }

        float m = logit;
        #pragma unroll
        for (int msk = 16; msk >= 1; msk >>= 1) m = fmaxf(m, __shfl_xor(m, msk));
        const float e = __expf(logit - m);
        float ssum = e;
        #pragma unroll
        for (int msk = 16; msk >= 1; msk >>= 1) ssum += __shfl_xor(ssum, msk);
        const float c = e / ssum;

        #pragma unroll
        for (int d = 0; d < DOUT; ++d) sacc[d] = fmaf(c, u[d], sacc[d]);
    }

    float* sp = s_out + (size_t)(b * NO + o) * DOUT;
    #pragma unroll
    for (int d = 0; d < DOUT; ++d) atomicAdd(&sp[d], sacc[d]);
}

__global__ __launch_bounds__(256)
void squash_update(const float* __restrict__ s, float* __restrict__ Vsum,
                   float* __restrict__ out, int last)
{
    const int tid  = threadIdx.x;
    const int pair = blockIdx.x * 8 + (tid >> 5);
    const int d    = tid & 31;
    const int idx  = pair * DOUT + d;

    const float val = s[idx];
    float sq = val * val;
    #pragma unroll
    for (int msk = 16; msk >= 1; msk >>= 1) sq += __shfl_xor(sq, msk);

    const float scale = sq / (1.f + sq) * rsqrtf(sq + EPSQ);
    const float v = val * scale;

    if (last) out[idx] = v;
    else      Vsum[idx] += v;
}

// ============================================================
extern "C" void kernel_launch(void* const* d_in, const int* in_sizes, int n_in,
                              void* d_out, int out_size, void* d_ws, size_t ws_size,
                              hipStream_t stream)
{
    const float* x = (const float*)d_in[0];   // [B, NI, DK]
    const float* W = (const float*)d_in[1];   // [NO, NI, DOUT, DK]
    float* out = (float*)d_out;               // [B, NO, DOUT]

    const size_t UBYTES = (size_t)B_ * NI * NO * DOUT * sizeof(ushort);  // 268 MB
    const size_t PBY    = (size_t)B_ * PSEG * 1024 * sizeof(float);      // 8 MB

    const size_t need_part   = 3 * PBY + UBYTES;
    const size_t need_atomic = (1 << 20) + UBYTES;

    if (ws_size >= need_part) {
        float* P0 = (float*)d_ws;
        float* P1 = (float*)((char*)d_ws + PBY);
        float* P2 = (float*)((char*)d_ws + 2 * PBY);
        ushort* U = (ushort*)((char*)d_ws + 3 * PBY);

        compute_uhat<<<dim3(NI * 2), dim3(512), 0, stream>>>(x, W, U);
        sum_u<true><<<dim3(B_ * PSEG), dim3(256), 0, stream>>>(U, P0);
        routing_mid<1, true><<<dim3(B_ * PSEG), dim3(256), 0, stream>>>(U, P0, P0, P1);
        routing_mid<2, true><<<dim3(B_ * PSEG), dim3(256), 0, stream>>>(U, P0, P1, P2);
        squash_final<true><<<dim3(B_ * NO * DOUT / 256), dim3(256), 0, stream>>>(P2, out);
    } else if (ws_size >= need_atomic) {
        float* s0 = (float*)d_ws;                 // 256 KB each
        float* s1 = s0 + (size_t)B_ * 1024;
        float* s2 = s1 + (size_t)B_ * 1024;
        ushort* U = (ushort*)((char*)d_ws + (1 << 20));

        hipMemsetAsync(d_ws, 0, (size_t)3 * B_ * 1024 * sizeof(float), stream);
        compute_uhat<<<dim3(NI * 2), dim3(512), 0, stream>>>(x, W, U);
        sum_u<false><<<dim3(B_ * PSEG), dim3(256), 0, stream>>>(U, s0);
        routing_mid<1, false><<<dim3(B_ * PSEG), dim3(256), 0, stream>>>(U, s0, s0, s1);
        routing_mid<2, false><<<dim3(B_ * PSEG), dim3(256), 0, stream>>>(U, s0, s1, s2);
        squash_final<false><<<dim3(B_ * NO * DOUT / 256), dim3(256), 0, stream>>>(s2, out);
    } else {
        float* s0 = (float*)d_ws;
        float* s1 = s0 + (size_t)B_ * 1024;
        hipMemsetAsync(d_ws, 0, (size_t)2 * B_ * 1024 * sizeof(float), stream);
        for (int r = 0; r < 3; ++r) {
            if (r > 0)
                hipMemsetAsync(s0, 0, (size_t)B_ * 1024 * sizeof(float), stream);
            routing_pass<<<dim3(GB * CHUNKS), dim3(512), 0, stream>>>(x, W, s1, s0);
            squash_update<<<dim3(B_ * NO / 8), dim3(256), 0, stream>>>(s0, s1, out, r == 2);
        }
    }
}

// Round 5
// 488.193 us; speedup vs baseline: 3.0561x; 3.0561x over previous
//
#include <hip/hip_runtime.h>

#define B_    64
#define NI    2048
#define DK    16
#define NO    32
#define DOUT  32
#define EPSQ  1e-7f

typedef unsigned u32x2 __attribute__((ext_vector_type(2)));
typedef unsigned u32x4 __attribute__((ext_vector_type(4)));

constexpr int PSEG = 32;   // partial segments per b (all reducers)

// ---------- helpers ----------
__device__ __forceinline__ unsigned pack2_bf16(float a, float b) {
    unsigned ua = __float_as_uint(a);
    unsigned ub = __float_as_uint(b);
    ua = (ua + 0x7fffu + ((ua >> 16) & 1u)) >> 16;   // RNE
    ub = (ub + 0x7fffu + ((ub >> 16) & 1u)) >> 16;
    return ua | (ub << 16);
}
__device__ __forceinline__ float bf_lo(unsigned w) { return __uint_as_float(w << 16); }
__device__ __forceinline__ float bf_hi(unsigned w) { return __uint_as_float(w & 0xffff0000u); }

// ============================================================
// u_hat layout (bf16/ushort): idx = (((b*NI + i)*4 + j)*NO + o)*8 + e, d = j*8+e
// per (b,i): 4 rows of 256 ushorts (512B each) = 2KB contiguous.
// ============================================================

// ------------------------------------------------------------
// compute_uhat (round-2 verified version: 125 us, VGPR 56, 0 LDS conflicts).
// Block = one i, 512 threads. NO forced min-occupancy (round-4 lesson:
// forcing 8 waves/EU capped VGPR at 32 -> 4 GB scratch spill traffic).
// ------------------------------------------------------------
constexpr int WSTRIDE = 516;   // 512 + 4 pad

__global__ __launch_bounds__(512)
void compute_uhat(const float* __restrict__ x, const float* __restrict__ W,
                  ushort* __restrict__ U)
{
    __shared__ float Ws[NO * WSTRIDE];   // 66048 B
    __shared__ float xs[B_ * DK];        // 4096 B
    const int i = blockIdx.x;
    const int t = threadIdx.x;

    // stage x[0:64, i, 0:16] (4 KB)
    if (t < 256) {
        const int b = t >> 2, k4 = t & 3;
        float4 v = *(const float4*)(x + ((size_t)b * NI + i) * DK + k4 * 4);
        *(float4*)&xs[b * DK + k4 * 4] = v;
    }

    // stage W[:, i, :, :] (64 KB) coalesced
    #pragma unroll
    for (int jj = 0; jj < 8; ++jj) {
        const int p  = t + 512 * jj;     // 0..4095
        const int oo = p >> 7;           // o
        const int cc = p & 127;          // float4 within o-row
        float4 v = ((const float4*)(W + ((size_t)oo * NI + i) * (DOUT * DK)))[cc];
        *(float4*)&Ws[oo * WSTRIDE + cc * 4] = v;
    }

    const int o  = t & 31;
    const int q  = (t >> 5) & 7;      // d = 4q .. 4q+3
    const int bh = t >> 8;            // 0/1

    __syncthreads();

    // LDS -> regs: W[o,i,4q:4q+4,0:16] = 64 consecutive floats
    float w[64];
    {
        const float* wr = &Ws[o * WSTRIDE + q * 64];
        #pragma unroll
        for (int m = 0; m < 16; ++m) {
            float4 v = *(const float4*)(wr + 4 * m);
            w[4*m+0] = v.x; w[4*m+1] = v.y; w[4*m+2] = v.z; w[4*m+3] = v.w;
        }
    }

    const int j = q >> 1, half = q & 1;

    for (int bb = 0; bb < 32; ++bb) {
        const int b = bh * 32 + bb;
        const float4* xv = (const float4*)&xs[b * DK];
        const float4 x0 = xv[0], x1 = xv[1], x2 = xv[2], x3 = xv[3];

        float acc[4];
        #pragma unroll
        for (int dl = 0; dl < 4; ++dl) {
            const float* wr = &w[dl * 16];
            float a;
            a  = wr[0]  * x0.x + wr[1]  * x0.y + wr[2]  * x0.z + wr[3]  * x0.w;
            a += wr[4]  * x1.x + wr[5]  * x1.y + wr[6]  * x1.z + wr[7]  * x1.w;
            a += wr[8]  * x2.x + wr[9]  * x2.y + wr[10] * x2.z + wr[11] * x2.w;
            a += wr[12] * x3.x + wr[13] * x3.y + wr[14] * x3.z + wr[15] * x3.w;
            acc[dl] = a;
        }

        u32x2 pk;
        pk.x = pack2_bf16(acc[0], acc[1]);
        pk.y = pack2_bf16(acc[2], acc[3]);
        const size_t off = ((((size_t)b * NI + i) * 4 + j) * NO + o) * 8 + half * 4;
        __builtin_nontemporal_store(pk, (u32x2*)(U + off));   // 8-byte aligned
    }
}

// ============================================================
// sum_u: s0[b,o,d] = (1/32) * sum_i u[b,i,o,d]. Block = (b, iseg of 64 i).
// 256 threads; c = t&127 owns one uint4 column, halves cover i-parity.
// LDS half-merge, then PART: non-atomic partial row / else atomics.
// ============================================================
template<bool PART>
__global__ __launch_bounds__(256)
void sum_u(const ushort* __restrict__ U, float* __restrict__ s0)
{
    __shared__ float red[128 * 9];     // pad 9 -> conflict-free
    const int t    = threadIdx.x;
    const int b    = blockIdx.x >> 5;
    const int iseg = blockIdx.x & 31;
    const int c    = t & 127;
    const int half = t >> 7;

    float acc[8];
    #pragma unroll
    for (int k = 0; k < 8; ++k) acc[k] = 0.f;

    const u32x4* up = (const u32x4*)U
        + ((size_t)b * NI + (size_t)iseg * (NI / PSEG) + half) * 128 + c;

    #pragma unroll 8
    for (int it = 0; it < (NI / PSEG) / 2; ++it) {
        u32x4 w = __builtin_nontemporal_load(up);
        up += 256;
        acc[0] += bf_lo(w.x); acc[1] += bf_hi(w.x);
        acc[2] += bf_lo(w.y); acc[3] += bf_hi(w.y);
        acc[4] += bf_lo(w.z); acc[5] += bf_hi(w.z);
        acc[6] += bf_lo(w.w); acc[7] += bf_hi(w.w);
    }

    if (half == 1) {
        #pragma unroll
        for (int k = 0; k < 8; ++k) red[c * 9 + k] = acc[k];
    }
    __syncthreads();
    if (half == 0) {
        #pragma unroll
        for (int k = 0; k < 8; ++k) acc[k] = (acc[k] + red[c * 9 + k]) * 0.03125f;

        const int o = c & 31, j = c >> 5;
        if (PART) {
            float* sp = s0 + ((size_t)(b * PSEG + iseg)) * 1024 + o * 32 + j * 8;
            float4 lo = {acc[0], acc[1], acc[2], acc[3]};
            float4 hi = {acc[4], acc[5], acc[6], acc[7]};
            *(float4*)sp = lo;
            *(float4*)(sp + 4) = hi;
        } else {
            float* sp = s0 + (size_t)b * 1024 + o * 32 + j * 8;
            #pragma unroll
            for (int k = 0; k < 8; ++k) atomicAdd(&sp[k], acc[k]);
        }
    }
}

// ---------- per-i routing math: logit -> softmax over o -> accumulate ----------
__device__ __forceinline__ void mid_proc(const u32x4 c0, const u32x4 c1,
                                         const float* vs, float* sacc)
{
    float lp = 0.f;
    #pragma unroll
    for (int wi = 0; wi < 4; ++wi) {
        lp = fmaf(vs[2*wi],         bf_lo(c0[wi]), lp);
        lp = fmaf(vs[2*wi + 1],     bf_hi(c0[wi]), lp);
        lp = fmaf(vs[8 + 2*wi],     bf_lo(c1[wi]), lp);
        lp = fmaf(vs[8 + 2*wi + 1], bf_hi(c1[wi]), lp);
    }
    lp += __shfl_xor(lp, 32);    // full logit on all 64 lanes

    float mx = lp;
    #pragma unroll
    for (int msk = 16; msk >= 1; msk >>= 1) mx = fmaxf(mx, __shfl_xor(mx, msk));
    const float e = __expf(lp - mx);
    float ss = e;
    #pragma unroll
    for (int msk = 16; msk >= 1; msk >>= 1) ss += __shfl_xor(ss, msk);
    const float cc = e / ss;

    #pragma unroll
    for (int wi = 0; wi < 4; ++wi) {
        sacc[2*wi]         = fmaf(cc, bf_lo(c0[wi]), sacc[2*wi]);
        sacc[2*wi + 1]     = fmaf(cc, bf_hi(c0[wi]), sacc[2*wi + 1]);
        sacc[8 + 2*wi]     = fmaf(cc, bf_lo(c1[wi]), sacc[8 + 2*wi]);
        sacc[8 + 2*wi + 1] = fmaf(cc, bf_hi(c1[wi]), sacc[8 + 2*wi + 1]);
    }
}

// ============================================================
// routing_mid v3 (r=1,2): block = (b, iseg of 64 i). 256 threads = 4 waves.
// One full wave per i: lane = (o = l&31, dh = l>>5 owning d = dh*16..+15).
// DUAL-STREAM: each wave runs two independent i-streams (i..i+7, i+8..i+15)
// -> 2x ILP on the softmax dependent chain, 2 KB in flight per wave.
// No forced min-occupancy (round-4 lesson).
// ============================================================
template<int R, bool PART>
__global__ __launch_bounds__(256)
void routing_mid(const ushort* __restrict__ U, const float* __restrict__ sA,
                 const float* __restrict__ sB, float* __restrict__ s_out)
{
    __shared__ float sblk[NO * DOUT];     // swizzled: (o,d) at [o*32 + ((d+o)&31)]
    __shared__ float vsh[NO][DOUT + 1];
    const int t    = threadIdx.x;
    const int b    = blockIdx.x >> 5;
    const int iseg = blockIdx.x & 31;
    const int i0   = iseg * (NI / PSEG);

    // ---- vs into vsh: thread = (oo = t>>3, dg = t&7) ----
    {
        const int oo = t >> 3;
        const int dg = t & 7;
        float4 sv;
        if (PART) {
            float4 a = {0.f, 0.f, 0.f, 0.f};
            for (int is = 0; is < PSEG; ++is) {
                float4 p = *(const float4*)(sA + ((size_t)(b * PSEG + is)) * 1024 + oo * 32 + dg * 4);
                a.x += p.x; a.y += p.y; a.z += p.z; a.w += p.w;
            }
            sv = a;
        } else {
            sv = *(const float4*)(sA + (size_t)b * 1024 + oo * 32 + dg * 4);
        }
        float sq = sv.x*sv.x + sv.y*sv.y + sv.z*sv.z + sv.w*sv.w;
        #pragma unroll
        for (int msk = 4; msk >= 1; msk >>= 1) sq += __shfl_xor(sq, msk);
        float sc = sq / (1.f + sq) * rsqrtf(sq + EPSQ);
        float v0 = sv.x * sc, v1 = sv.y * sc, v2 = sv.z * sc, v3 = sv.w * sc;
        if (R == 2) {
            float4 s2v;
            if (PART) {
                float4 a = {0.f, 0.f, 0.f, 0.f};
                for (int is = 0; is < PSEG; ++is) {
                    float4 p = *(const float4*)(sB + ((size_t)(b * PSEG + is)) * 1024 + oo * 32 + dg * 4);
                    a.x += p.x; a.y += p.y; a.z += p.z; a.w += p.w;
                }
                s2v = a;
            } else {
                s2v = *(const float4*)(sB + (size_t)b * 1024 + oo * 32 + dg * 4);
            }
            float sq2 = s2v.x*s2v.x + s2v.y*s2v.y + s2v.z*s2v.z + s2v.w*s2v.w;
            #pragma unroll
            for (int msk = 4; msk >= 1; msk >>= 1) sq2 += __shfl_xor(sq2, msk);
            float sc2 = sq2 / (1.f + sq2) * rsqrtf(sq2 + EPSQ);
            v0 += s2v.x * sc2; v1 += s2v.y * sc2; v2 += s2v.z * sc2; v3 += s2v.w * sc2;
        }
        vsh[oo][dg * 4 + 0] = v0; vsh[oo][dg * 4 + 1] = v1;
        vsh[oo][dg * 4 + 2] = v2; vsh[oo][dg * 4 + 3] = v3;
    }
    for (int n = t; n < NO * DOUT; n += 256) sblk[n] = 0.f;
    __syncthreads();

    const int lane = t & 63;
    const int o    = lane & 31;
    const int dh   = lane >> 5;       // d-half: d = dh*16 + ld
    const int wv   = t >> 6;          // wave 0..3 -> 16 i each (two streams of 8)

    float vs[16];
    #pragma unroll
    for (int ld = 0; ld < 16; ++ld) vs[ld] = vsh[o][dh * 16 + ld];

    float sacc[16];
    #pragma unroll
    for (int ld = 0; ld < 16; ++ld) sacc[ld] = 0.f;

    // per (b,i): 4*NO u32x4; rows 2dh, 2dh+1 -> d = 16dh + (0..15)
    const u32x4* upA = (const u32x4*)U
        + (((size_t)b * NI + i0 + wv * 16) * 4 + 2 * dh) * NO + o;
    const u32x4* upB = upA + (size_t)8 * 4 * NO;   // stream B: i+8

    u32x4 a0 = __builtin_nontemporal_load(upA);
    u32x4 a1 = __builtin_nontemporal_load(upA + NO);
    u32x4 b0 = __builtin_nontemporal_load(upB);
    u32x4 b1 = __builtin_nontemporal_load(upB + NO);
    upA += 4 * NO;
    upB += 4 * NO;

    for (int ii = 0; ii < 8; ++ii) {
        u32x4 na0 = {}, na1 = {}, nb0 = {}, nb1 = {};
        const bool more = (ii < 7);   // uniform
        if (more) {
            na0 = __builtin_nontemporal_load(upA);
            na1 = __builtin_nontemporal_load(upA + NO);
            nb0 = __builtin_nontemporal_load(upB);
            nb1 = __builtin_nontemporal_load(upB + NO);
            upA += 4 * NO;
            upB += 4 * NO;
        }

        mid_proc(a0, a1, vs, sacc);   // two independent chains -> compiler
        mid_proc(b0, b1, vs, sacc);   // interleaves them (2x chain ILP)

        if (more) { a0 = na0; a1 = na1; b0 = nb0; b1 = nb1; }
    }

    // block reduce (swizzled -> 2-way max, free)
    #pragma unroll
    for (int ld = 0; ld < 16; ++ld) {
        const int d = dh * 16 + ld;
        atomicAdd(&sblk[o * 32 + ((d + o) & 31)], sacc[ld]);
    }
    __syncthreads();

    if (PART) {
        float* sp = s_out + ((size_t)(b * PSEG + iseg)) * 1024;
        for (int n = t; n < NO * DOUT; n += 256) {
            const int oo = n >> 5, dd = n & 31;
            sp[n] = sblk[oo * 32 + ((dd + oo) & 31)];
        }
    } else {
        float* sp = s_out + (size_t)b * 1024;
        for (int n = t; n < NO * DOUT; n += 256) {
            const int oo = n >> 5, dd = n & 31;
            atomicAdd(&sp[n], sblk[oo * 32 + ((dd + oo) & 31)]);
        }
    }
}

// ============================================================
// final v = squash(s2) -> out.  PART: reduce 32 partial rows first.
// ============================================================
template<bool PART>
__global__ __launch_bounds__(256)
void squash_final(const float* __restrict__ s, float* __restrict__ out)
{
    const int g = blockIdx.x * 256 + threadIdx.x;   // b*1024 + o*32 + d
    float val;
    if (PART) {
        const int b = g >> 10, slot = g & 1023;
        float a = 0.f;
        for (int is = 0; is < PSEG; ++is)
            a += s[((size_t)(b * PSEG + is)) * 1024 + slot];
        val = a;
    } else {
        val = s[g];
    }
    float sq = val * val;
    #pragma unroll
    for (int msk = 16; msk >= 1; msk >>= 1) sq += __shfl_xor(sq, msk);
    const float scale = sq / (1.f + sq) * rsqrtf(sq + EPSQ);
    out[g] = val * scale;
}

// ============================================================
// FALLBACK PATH (fused recompute; used if ws too small)
// ============================================================
constexpr int BTILE  = 16;
constexpr int ITILE  = 32;
constexpr int CHUNKS = NI / ITILE;
constexpr int GB     = B_ / BTILE;
constexpr int WROW   = DOUT * DK + 4;

__global__ __launch_bounds__(512)
void routing_pass(const float* __restrict__ x, const float* __restrict__ W,
                  const float* __restrict__ Vsum, float* __restrict__ s_out)
{
    __shared__ float W_s[NO * WROW];
    const int tid   = threadIdx.x;
    const int o     = tid & 31;
    const int bl    = tid >> 5;
    const int chunk = blockIdx.x & (CHUNKS - 1);
    const int gb    = blockIdx.x / CHUNKS;
    const int b     = gb * BTILE + bl;

    float vs[DOUT];
    {
        const float4* vp = (const float4*)(Vsum + (size_t)(b * NO + o) * DOUT);
        #pragma unroll
        for (int qq = 0; qq < 8; ++qq) {
            float4 t2 = vp[qq];
            vs[4*qq+0] = t2.x; vs[4*qq+1] = t2.y; vs[4*qq+2] = t2.z; vs[4*qq+3] = t2.w;
        }
    }
    float sacc[DOUT];
    #pragma unroll
    for (int d = 0; d < DOUT; ++d) sacc[d] = 0.f;

    const int o_ld = tid >> 4;
    const int lpos = tid & 15;

    for (int ii = 0; ii < ITILE; ++ii) {
        const int i = chunk * ITILE + ii;
        __syncthreads();
        const float4* wsrc = (const float4*)W + ((size_t)o_ld * NI + i) * (DOUT * DK / 4);
        #pragma unroll
        for (int jj = 0; jj < 8; ++jj) {
            const int f4pos = lpos + 16 * jj;
            float4 v = wsrc[f4pos];
            *(float4*)&W_s[o_ld * WROW + f4pos * 4] = v;
        }
        __syncthreads();

        const float4* xg = (const float4*)(x + ((size_t)b * NI + i) * DK);
        const float4 xr0 = xg[0], xr1 = xg[1], xr2 = xg[2], xr3 = xg[3];

        float u[DOUT];
        float logit = 0.f;
        const float* wrow = &W_s[o * WROW];
        #pragma unroll
        for (int d = 0; d < DOUT; ++d) {
            const float4 w0 = *(const float4*)(wrow + d * DK + 0);
            const float4 w1 = *(const float4*)(wrow + d * DK + 4);
            const float4 w2 = *(const float4*)(wrow + d * DK + 8);
            const float4 w3 = *(const float4*)(wrow + d * DK + 12);
            float acc;
            acc  = w0.x * xr0.x + w0.y * xr0.y + w0.z * xr0.z + w0.w * xr0.w;
            acc += w1.x * xr1.x + w1.y * xr1.y + w1.z * xr1.z + w1.w * xr1.w;
            acc += w2.x * xr2.x + w2.y * xr2.y + w2.z * xr2.z + w2.w * xr2.w;
            acc += w3.x * xr3.x + w3.y * xr3.y + w3.z * xr3.z + w3.w * xr3.w;
            u[d]  = acc;
            logit = fmaf(vs[d], acc, logit);
        }

        float m = logit;
        #pragma unroll
        for (int msk = 16; msk >= 1; msk >>= 1) m = fmaxf(m, __shfl_xor(m, msk));
        const float e = __expf(logit - m);
        float ssum = e;
        #pragma unroll
        for (int msk = 16; msk >= 1; msk >>= 1) ssum += __shfl_xor(ssum, msk);
        const float c = e / ssum;

        #pragma unroll
        for (int d = 0; d < DOUT; ++d) sacc[d] = fmaf(c, u[d], sacc[d]);
    }

    float* sp = s_out + (size_t)(b * NO + o) * DOUT;
    #pragma unroll
    for (int d = 0; d < DOUT; ++d) atomicAdd(&sp[d], sacc[d]);
}

__global__ __launch_bounds__(256)
void squash_update(const float* __restrict__ s, float* __restrict__ Vsum,
                   float* __restrict__ out, int last)
{
    const int tid  = threadIdx.x;
    const int pair = blockIdx.x * 8 + (tid >> 5);
    const int d    = tid & 31;
    const int idx  = pair * DOUT + d;

    const float val = s[idx];
    float sq = val * val;
    #pragma unroll
    for (int msk = 16; msk >= 1; msk >>= 1) sq += __shfl_xor(sq, msk);

    const float scale = sq / (1.f + sq) * rsqrtf(sq + EPSQ);
    const float v = val * scale;

    if (last) out[idx] = v;
    else      Vsum[idx] += v;
}

// ============================================================
extern "C" void kernel_launch(void* const* d_in, const int* in_sizes, int n_in,
                              void* d_out, int out_size, void* d_ws, size_t ws_size,
                              hipStream_t stream)
{
    const float* x = (const float*)d_in[0];   // [B, NI, DK]
    const float* W = (const float*)d_in[1];   // [NO, NI, DOUT, DK]
    float* out = (float*)d_out;               // [B, NO, DOUT]

    const size_t UBYTES = (size_t)B_ * NI * NO * DOUT * sizeof(ushort);  // 268 MB
    const size_t PBY    = (size_t)B_ * PSEG * 1024 * sizeof(float);      // 8 MB

    const size_t need_part   = 3 * PBY + UBYTES;
    const size_t need_atomic = (1 << 20) + UBYTES;

    if (ws_size >= need_part) {
        float* P0 = (float*)d_ws;
        float* P1 = (float*)((char*)d_ws + PBY);
        float* P2 = (float*)((char*)d_ws + 2 * PBY);
        ushort* U = (ushort*)((char*)d_ws + 3 * PBY);

        compute_uhat<<<dim3(NI), dim3(512), 0, stream>>>(x, W, U);
        sum_u<true><<<dim3(B_ * PSEG), dim3(256), 0, stream>>>(U, P0);
        routing_mid<1, true><<<dim3(B_ * PSEG), dim3(256), 0, stream>>>(U, P0, P0, P1);
        routing_mid<2, true><<<dim3(B_ * PSEG), dim3(256), 0, stream>>>(U, P0, P1, P2);
        squash_final<true><<<dim3(B_ * NO * DOUT / 256), dim3(256), 0, stream>>>(P2, out);
    } else if (ws_size >= need_atomic) {
        float* s0 = (float*)d_ws;                 // 256 KB each
        float* s1 = s0 + (size_t)B_ * 1024;
        float* s2 = s1 + (size_t)B_ * 1024;
        ushort* U = (ushort*)((char*)d_ws + (1 << 20));

        hipMemsetAsync(d_ws, 0, (size_t)3 * B_ * 1024 * sizeof(float), stream);
        compute_uhat<<<dim3(NI), dim3(512), 0, stream>>>(x, W, U);
        sum_u<false><<<dim3(B_ * PSEG), dim3(256), 0, stream>>>(U, s0);
        routing_mid<1, false><<<dim3(B_ * PSEG), dim3(256), 0, stream>>>(U, s0, s0, s1);
        routing_mid<2, false><<<dim3(B_ * PSEG), dim3(256), 0, stream>>>(U, s0, s1, s2);
        squash_final<false><<<dim3(B_ * NO * DOUT / 256), dim3(256), 0, stream>>>(s2, out);
    } else {
        float* s0 = (float*)d_ws;
        float* s1 = s0 + (size_t)B_ * 1024;
        hipMemsetAsync(d_ws, 0, (size_t)2 * B_ * 1024 * sizeof(float), stream);
        for (int r = 0; r < 3; ++r) {
            if (r > 0)
                hipMemsetAsync(s0, 0, (size_t)B_ * 1024 * sizeof(float), stream);
            routing_pass<<<dim3(GB * CHUNKS), dim3(512), 0, stream>>>(x, W, s1, s0);
            squash_update<<<dim3(B_ * NO / 8), dim3(256), 0, stream>>>(s0, s1, out, r == 2);
        }
    }
}